// Round 9
// baseline (11422.308 us; speedup 1.0000x reference)
//
#include <hip/hip_runtime.h>
#include <hip/hip_bf16.h>
#include <stdint.h>
#include <stddef.h>

#define B_SZ   4096
#define U_SZ   1024
#define SEQ    5
#define TSTEPS 200
#define STEPS  204          // 5 warmup + 199 decode LSTM steps

typedef __bf16 bf16_t;
typedef __bf16 bf16x8 __attribute__((ext_vector_type(8)));
typedef float  f32x4  __attribute__((ext_vector_type(4)));

#define AS1 __attribute__((address_space(1)))
#define AS3 __attribute__((address_space(3)))

#define LOAD_LDS16(gp, lp) \
    __builtin_amdgcn_global_load_lds((const AS1 unsigned int*)(gp), \
                                     (AS3 unsigned int*)(lp), 16, 0, 0)

__device__ __forceinline__ float fsig(float x) {
    return 1.0f / (1.0f + __expf(-x));
}
__device__ __forceinline__ float ftanh(float x) {
    x = fminf(fmaxf(x, -15.0f), 15.0f);
    float e = __expf(2.0f * x);
    return (e - 1.0f) / (e + 1.0f);
}

// ---------------------------------------------------------------------------
// Pack R (1024 x 4096 fp32 row-major) into bf16 panels, one per ub (32 u's),
// with XOR-swizzled 16B slots to kill LDS bank conflicts (round-6 verbatim).
// ---------------------------------------------------------------------------
__global__ void pack_R(const float* __restrict__ R, bf16_t* __restrict__ Rp) {
    int idx = blockIdx.x * 256 + threadIdx.x;   // 4,194,304 total
    int e    = idx & 7;
    int slot = (idx >> 3) & 7;                  // physical 16B slot in row
    int c    = (idx >> 6) & 127;
    int kb   = (idx >> 13) & 15;
    int ub   = idx >> 17;
    int g  = (c >> 4) & 3;
    int wc = c >> 6;
    int cl = c & 15;
    int n  = g * 1024 + ub * 32 + wc * 16 + cl;
    int k  = kb * 64 + ((slot ^ (c & 7)) << 3) + e;   // un-swizzle -> logical k
    Rp[idx] = (bf16_t)R[(size_t)k * 4096 + n];
}

// ---------------------------------------------------------------------------
// One LSTM step (round-6 base) with A DIRECT GLOBAL->REGISTER fragments
// (no A LDS path) and DOUBLE-BUFFERED B (staged a full iteration ahead):
//   per kb: [s_waitcnt vmcnt(4) lgkmcnt(0)] [s_barrier]   <- ONE barrier
//           STAGE_B(kb+1) -> other parity   (full-iter cover, L2-hit)
//           af(kb,kh1)->regs ; dsread bfr(kh0) ; 32 MFMA (afA)
//           af(kb+1,kh0)->regs ; dsread bfr(kh1) ; 32 MFMA (afB)
//   vmcnt(4) leaves only the newest 4 af loads in flight -> B(kb) landed.
//   af/bfr waits are compiler-tracked (normal loads).  B-overwrite safety =
//   round 6's lgkmcnt(0)-before-barrier argument.
// LDS: B 2x32 KB + lsX = 64.5 KB -> 2 blocks/CU kept.
// ---------------------------------------------------------------------------
__global__ __launch_bounds__(256, 2)
void lstm_step(const bf16_t* __restrict__ hin,
               bf16_t* __restrict__ hout,
               float* __restrict__ cst,
               const bf16_t* __restrict__ Rp,
               const float* __restrict__ Wx,     // (4096,)
               const float* __restrict__ bias,   // (4096,)
               const float* __restrict__ w1,     // (1024,)
               const float* __restrict__ b1,
               const float* __restrict__ w2,
               const float* __restrict__ b2,
               const float* __restrict__ inputs, // [4096,5]
               float* __restrict__ praw,         // 3*4096
               float* __restrict__ out,          // [4096,200]
               int t)
{
    __shared__ __align__(16) bf16_t lsB[2][2][8192];     // 64 KB (dbuf x 2T)
    __shared__ float lsX[128];

    const int tid  = threadIdx.x;
    const int wave = tid >> 6;
    const int lane = tid & 63;
    const int p    = blockIdx.x;   // 0..15 fastest -> panels pinned per XCD
    const int G    = blockIdx.y;   // 0..31
    const int l15  = lane & 15;
    const int quad = lane >> 4;
    const int rbase = (wave >> 1) * 64;
    const int wc    = wave & 1;

    float*       pr_acc  = praw + (size_t)(t % 3) * B_SZ;
    const float* pr_read = praw + (size_t)((t + 2) % 3) * B_SZ;
    float*       pr_zero = praw + (size_t)((t + 1) % 3) * B_SZ;

    const bf16_t* Ap  = hin + (size_t)G * 128 * U_SZ;
    const bf16_t* Bp0 = Rp + (size_t)(2 * p) * 131072;
    const bf16_t* Bp1 = Bp0 + 131072;
    // A fragment base: lane reads 16B at row (rbase+mi*16+l15),
    // col kb*64 + (kh*4+quad)*8  ->  Arow + mi*16*U_SZ + kb*64 + kh*32
    const bf16_t* Arow = Ap + (size_t)(rbase + l15) * U_SZ + quad * 8;

    // ---- prologue: x for my 128 rows (+ out write + praw-slot zero) ----
    if (tid < 128) {
        int row = G * 128 + tid;
        float x;
        if (t < SEQ) {
            x = inputs[row * SEQ + t];
        } else {
            float x1 = fmaxf(pr_read[row] + b1[0], 0.f);
            x = (t == SEQ) ? x1 : x1 * w2[0] + b2[0];
            if (p == 0) out[(size_t)row * TSTEPS + (t - SEQ)] = x;
        }
        lsX[tid] = x;
        if (p == 0) pr_zero[row] = 0.f;
    }

    // ---- B stage helper (round-6 pattern, into a parity) ----
    auto STAGE_B = [&](int ksrc, int par) {
        #pragma unroll
        for (int i = 0; i < 4; ++i) {
            int chunk = wave * 4 + i;
            LOAD_LDS16(Bp0 + (size_t)ksrc * 8192 + chunk * 512 + lane * 8,
                       &lsB[par][0][chunk * 512]);
            LOAD_LDS16(Bp1 + (size_t)ksrc * 8192 + chunk * 512 + lane * 8,
                       &lsB[par][1][chunk * 512]);
        }
    };

    // ---- pipeline fill: B(0) -> parity 0; af(0,kh0) -> regs ----
    STAGE_B(0, 0);
    bf16x8 afA[4], afB[4];
    #pragma unroll
    for (int mi = 0; mi < 4; ++mi)
        afA[mi] = *(const bf16x8*)(Arow + (size_t)mi * 16 * U_SZ);

    f32x4 acc[2][4][4] = {};

    #pragma clang loop unroll(disable)
    for (int kb = 0; kb < 16; ++kb) {
        // B(kb) landed (only newest 4 af loads may remain); my ds_reads done
        asm volatile("s_waitcnt vmcnt(4) lgkmcnt(0)" ::: "memory");
        __builtin_amdgcn_sched_barrier(0);
        __builtin_amdgcn_s_barrier();
        __builtin_amdgcn_sched_barrier(0);

        if (kb < 15) STAGE_B(kb + 1, (kb + 1) & 1);   // full-iter cover

        #pragma unroll
        for (int mi = 0; mi < 4; ++mi)                // af(kb, kh=1)
            afB[mi] = *(const bf16x8*)(Arow + (size_t)mi * 16 * U_SZ
                                            + kb * 64 + 32);

        const bf16_t* lb = &lsB[kb & 1][0][0];

        // ---- kh = 0: bfr from LDS, MFMA on afA ----
        {
            const int sw = ((quad ^ (lane & 7)) << 3);
            bf16x8 bfr[2][4];
            #pragma unroll
            for (int T = 0; T < 2; ++T)
                #pragma unroll
                for (int ni = 0; ni < 4; ++ni)
                    bfr[T][ni] = *(const bf16x8*)
                        &lb[T * 8192 + (wc * 64 + ni * 16 + l15) * 64 + sw];
            __builtin_amdgcn_s_setprio(1);
            #pragma unroll
            for (int T = 0; T < 2; ++T)
                #pragma unroll
                for (int mi = 0; mi < 4; ++mi)
                    #pragma unroll
                    for (int ni = 0; ni < 4; ++ni)
                        acc[T][mi][ni] = __builtin_amdgcn_mfma_f32_16x16x32_bf16(
                            afA[mi], bfr[T][ni], acc[T][mi][ni], 0, 0, 0);
            __builtin_amdgcn_s_setprio(0);
        }

        #pragma unroll
        for (int mi = 0; mi < 4; ++mi)                // af(kb+1, kh=0)
            afA[mi] = *(const bf16x8*)(Arow + (size_t)mi * 16 * U_SZ
                                            + ((kb + 1) & 15) * 64);

        // ---- kh = 1: bfr from LDS, MFMA on afB ----
        {
            const int sw = (((4 + quad) ^ (lane & 7)) << 3);
            bf16x8 bfr[2][4];
            #pragma unroll
            for (int T = 0; T < 2; ++T)
                #pragma unroll
                for (int ni = 0; ni < 4; ++ni)
                    bfr[T][ni] = *(const bf16x8*)
                        &lb[T * 8192 + (wc * 64 + ni * 16 + l15) * 64 + sw];
            __builtin_amdgcn_s_setprio(1);
            #pragma unroll
            for (int T = 0; T < 2; ++T)
                #pragma unroll
                for (int mi = 0; mi < 4; ++mi)
                    #pragma unroll
                    for (int ni = 0; ni < 4; ++ni)
                        acc[T][mi][ni] = __builtin_amdgcn_mfma_f32_16x16x32_bf16(
                            afB[mi], bfr[T][ni], acc[T][mi][ni], 0, 0, 0);
            __builtin_amdgcn_s_setprio(0);
        }
    }

    // ---- epilogue: gates, c RMW (global fp32), h write, pred partials ----
    int uu[2];
    uu[0] = (2 * p) * 32 + wc * 16 + l15;
    uu[1] = uu[0] + 32;
    float g_b[2][4], g_w[2][4], w1u[2];
    #pragma unroll
    for (int T = 0; T < 2; ++T) {
        #pragma unroll
        for (int g = 0; g < 4; ++g) {
            g_b[T][g] = bias[g * 1024 + uu[T]];
            g_w[T][g] = Wx[g * 1024 + uu[T]];
        }
        w1u[T] = w1[uu[T]];
    }
    const bool do_pred = (t >= SEQ - 1);

    #pragma unroll
    for (int mi = 0; mi < 4; ++mi) {
        #pragma unroll
        for (int r = 0; r < 4; ++r) {
            int rl   = rbase + mi * 16 + quad * 4 + r;
            int brow = G * 128 + rl;
            float xv = lsX[rl];
            float ps = 0.f;
            #pragma unroll
            for (int T = 0; T < 2; ++T) {
                float zi = acc[T][mi][0][r] + g_b[T][0] + xv * g_w[T][0];
                float zf = acc[T][mi][1][r] + g_b[T][1] + xv * g_w[T][1];
                float zg = acc[T][mi][2][r] + g_b[T][2] + xv * g_w[T][2];
                float zo = acc[T][mi][3][r] + g_b[T][3] + xv * g_w[T][3];
                float ig = fsig(zi), fg = fsig(zf);
                float gg = ftanh(zg), og = fsig(zo);
                size_t off = (size_t)brow * U_SZ + uu[T];
                float cn = fg * cst[off] + ig * gg;
                cst[off] = cn;
                float hv = og * ftanh(cn);
                hout[off] = (bf16_t)hv;
                ps += hv * w1u[T];
            }
            if (do_pred) {
                ps += __shfl_xor(ps, 1);
                ps += __shfl_xor(ps, 2);
                ps += __shfl_xor(ps, 4);
                ps += __shfl_xor(ps, 8);
                if (l15 == 0) atomicAdd(&pr_acc[brow], ps);
            }
        }
    }
}

// final output slot 199 from praw of step 203 (203 % 3 == 2)
__global__ void pred_final(const float* __restrict__ praw,
                           const float* __restrict__ b1,
                           const float* __restrict__ w2,
                           const float* __restrict__ b2,
                           float* __restrict__ out)
{
    int row = blockIdx.x * 256 + threadIdx.x;
    float x1 = fmaxf(praw[2 * B_SZ + row] + b1[0], 0.f);
    out[(size_t)row * TSTEPS + 199] = x1 * w2[0] + b2[0];
}

extern "C" void kernel_launch(void* const* d_in, const int* in_sizes, int n_in,
                              void* d_out, int out_size, void* d_ws, size_t ws_size,
                              hipStream_t stream) {
    const float* inputs = (const float*)d_in[0];   // [4096,5,1]
    const float* Wx     = (const float*)d_in[1];   // [1,4096]
    const float* R      = (const float*)d_in[2];   // [1024,4096]
    const float* bias   = (const float*)d_in[3];   // [4096]
    const float* w1     = (const float*)d_in[4];   // [1024,1]
    const float* b1     = (const float*)d_in[5];
    const float* w2     = (const float*)d_in[6];
    const float* b2     = (const float*)d_in[7];
    float* out = (float*)d_out;

    char* ws = (char*)d_ws;
    const size_t RP_BYTES = (size_t)32 * 131072 * 2;          // 8 MB
    const size_t H_BYTES  = (size_t)B_SZ * U_SZ * 2;          // 8 MB
    const size_t C_BYTES  = (size_t)B_SZ * U_SZ * 4;          // 16 MB
    bf16_t* Rp   = (bf16_t*)ws;                ws += RP_BYTES;
    bf16_t* h0   = (bf16_t*)ws;                ws += H_BYTES;
    bf16_t* h1   = (bf16_t*)ws;                ws += H_BYTES;
    float*  cbuf = (float*)ws;                 ws += C_BYTES;
    float*  praw = (float*)ws;                 ws += 3 * B_SZ * 4;
    bf16_t* hb[2] = {h0, h1};

    hipMemsetAsync(h0, 0, H_BYTES, stream);
    hipMemsetAsync(cbuf, 0, C_BYTES, stream);
    hipMemsetAsync(praw, 0, 3 * B_SZ * 4, stream);

    pack_R<<<16384, 256, 0, stream>>>(R, Rp);

    dim3 grid(16, 32);   // p fastest -> B panels pinned per XCD
    int cur = 0;
    for (int t = 0; t < STEPS; ++t) {
        lstm_step<<<grid, 256, 0, stream>>>(hb[cur], hb[1 - cur], cbuf, Rp,
                                            Wx, bias, w1, b1, w2, b2,
                                            inputs, praw, out, t);
        cur ^= 1;
    }
    pred_final<<<16, 256, 0, stream>>>(praw, b1, w2, b2, out);
}

// Round 10
// 8603.355 us; speedup vs baseline: 1.3277x; 1.3277x over previous
//
#include <hip/hip_runtime.h>
#include <hip/hip_bf16.h>
#include <stdint.h>
#include <stddef.h>

#define B_SZ   4096
#define U_SZ   1024
#define SEQ    5
#define TSTEPS 200
#define STEPS  204          // 5 warmup + 199 decode LSTM steps

typedef __bf16 bf16_t;
typedef __bf16 bf16x8 __attribute__((ext_vector_type(8)));
typedef float  f32x4  __attribute__((ext_vector_type(4)));

#define AS1 __attribute__((address_space(1)))
#define AS3 __attribute__((address_space(3)))

#define LOAD_LDS16(gp, lp) \
    __builtin_amdgcn_global_load_lds((const AS1 unsigned int*)(gp), \
                                     (AS3 unsigned int*)(lp), 16, 0, 0)

__device__ __forceinline__ float fsig(float x) {
    return 1.0f / (1.0f + __expf(-x));
}
__device__ __forceinline__ float ftanh(float x) {
    x = fminf(fmaxf(x, -15.0f), 15.0f);
    float e = __expf(2.0f * x);
    return (e - 1.0f) / (e + 1.0f);
}

// ---------------------------------------------------------------------------
// Pack R (1024 x 4096 fp32 row-major) into bf16 panels, one per ub (32 u's),
// with XOR-swizzled 16B slots to kill LDS bank conflicts (round-6 verbatim).
// ---------------------------------------------------------------------------
__global__ void pack_R(const float* __restrict__ R, bf16_t* __restrict__ Rp) {
    int idx = blockIdx.x * 256 + threadIdx.x;   // 4,194,304 total
    int e    = idx & 7;
    int slot = (idx >> 3) & 7;                  // physical 16B slot in row
    int c    = (idx >> 6) & 127;
    int kb   = (idx >> 13) & 15;
    int ub   = idx >> 17;
    int g  = (c >> 4) & 3;
    int wc = c >> 6;
    int cl = c & 15;
    int n  = g * 1024 + ub * 32 + wc * 16 + cl;
    int k  = kb * 64 + ((slot ^ (c & 7)) << 3) + e;   // un-swizzle -> logical k
    Rp[idx] = (bf16_t)R[(size_t)k * 4096 + n];
}

// ---------------------------------------------------------------------------
// One LSTM step — round-6 kernel verbatim EXCEPT the (p,G) decode:
// 2-D XCD tiling.  Under the bid%8 round-robin dispatch heuristic, each XCD
// gets a 4p x 16G tile (panels 2 MB + h 4 MB per XCD per step) instead of
// 2p x 32G (1 MB + 8 MB): chip-wide cross-die h reads halve (64->32 MB/step)
// and panel eviction pressure halves.  Mapping is bijective, so correctness
// never depends on the dispatch heuristic (G16-safe).
// ---------------------------------------------------------------------------
__global__ __launch_bounds__(256, 2)
void lstm_step(const bf16_t* __restrict__ hin,
               bf16_t* __restrict__ hout,
               float* __restrict__ cst,
               const bf16_t* __restrict__ Rp,
               const float* __restrict__ Wx,     // (4096,)
               const float* __restrict__ bias,   // (4096,)
               const float* __restrict__ w1,     // (1024,)
               const float* __restrict__ b1,
               const float* __restrict__ w2,
               const float* __restrict__ b2,
               const float* __restrict__ inputs, // [4096,5]
               float* __restrict__ praw,         // 3*4096
               float* __restrict__ out,          // [4096,200]
               int t)
{
    __shared__ __align__(16) bf16_t lsA[2][8192];        // 32 KB (dbuf)
    __shared__ __align__(16) bf16_t lsB[2][8192];        // 32 KB
    __shared__ float lsX[128];

    const int tid  = threadIdx.x;
    const int wave = tid >> 6;
    const int lane = tid & 63;
    // ---- 2-D XCD tiling: xcd = bid&7 owns p in [ (xcd&3)*4, +4 ),
    //                                   G in [ (xcd>>2)*16, +16 ) ----
    const int bid  = blockIdx.x + 16 * blockIdx.y;   // x fastest (dispatch)
    const int xcd  = bid & 7;
    const int j    = bid >> 3;                       // 0..63 within XCD
    const int p    = (xcd & 3) * 4 + (j & 3);        // 0..15
    const int G    = (xcd >> 2) * 16 + (j >> 2);     // 0..31
    const int l15  = lane & 15;
    const int quad = lane >> 4;
    const int rbase = (wave >> 1) * 64;
    const int wc    = wave & 1;
    const int a_kk  = (((lane & 7) ^ (lane >> 3)) << 3);

    float*       pr_acc  = praw + (size_t)(t % 3) * B_SZ;
    const float* pr_read = praw + (size_t)((t + 2) % 3) * B_SZ;
    float*       pr_zero = praw + (size_t)((t + 1) % 3) * B_SZ;

    const bf16_t* Ap  = hin + (size_t)G * 128 * U_SZ;
    const bf16_t* Bp0 = Rp + (size_t)(2 * p) * 131072;
    const bf16_t* Bp1 = Bp0 + 131072;

    // ---- prologue staging: A(0) -> lsA[0], B(0) -> lsB ----
    #pragma unroll
    for (int i = 0; i < 4; ++i) {
        int chunk = wave * 4 + i;
        int m  = chunk * 8 + (lane >> 3);
        LOAD_LDS16(Ap + (size_t)m * U_SZ + a_kk, &lsA[0][chunk * 512]);
    }
    #pragma unroll
    for (int i = 0; i < 4; ++i) {
        int chunk = wave * 4 + i;
        LOAD_LDS16(Bp0 + chunk * 512 + lane * 8, &lsB[0][chunk * 512]);
        LOAD_LDS16(Bp1 + chunk * 512 + lane * 8, &lsB[1][chunk * 512]);
    }

    // ---- prologue: x for my 128 rows (+ out write + praw-slot zero) ----
    if (tid < 128) {
        int row = G * 128 + tid;
        float x;
        if (t < SEQ) {
            x = inputs[row * SEQ + t];
        } else {
            float x1 = fmaxf(pr_read[row] + b1[0], 0.f);
            x = (t == SEQ) ? x1 : x1 * w2[0] + b2[0];
            if (p == 0) out[(size_t)row * TSTEPS + (t - SEQ)] = x;
        }
        lsX[tid] = x;
        if (p == 0) pr_zero[row] = 0.f;
    }

    // ---- pipelined K-loop (round-6 verbatim) ----
    f32x4 acc[2][4][4] = {};

    for (int kb = 0; kb < 16; ++kb) {
        __syncthreads();            // drains A(kb) + B(kb) (both covered)

        if (kb < 15) {              // A(kb+1) -> other parity, longest cover
            const int kn = kb + 1;
            #pragma unroll
            for (int i = 0; i < 4; ++i) {
                int chunk = wave * 4 + i;
                int m  = chunk * 8 + (lane >> 3);
                LOAD_LDS16(Ap + (size_t)m * U_SZ + kn * 64 + a_kk,
                           &lsA[kn & 1][chunk * 512]);
            }
        }

        // ds_read all fragments for kb into registers
        const bf16_t* la = &lsA[kb & 1][0];
        bf16x8 af[2][4], bfr[2][2][4];
        #pragma unroll
        for (int kh = 0; kh < 2; ++kh) {
            int sw = (((kh * 4 + quad) ^ (lane & 7)) << 3);
            #pragma unroll
            for (int mi = 0; mi < 4; ++mi)
                af[kh][mi] = *(const bf16x8*)&la[(rbase + mi * 16 + l15) * 64 + sw];
            #pragma unroll
            for (int T = 0; T < 2; ++T)
                #pragma unroll
                for (int ni = 0; ni < 4; ++ni)
                    bfr[kh][T][ni] = *(const bf16x8*)
                        &lsB[T][(wc * 64 + ni * 16 + l15) * 64 + sw];
        }

        // my LDS reads complete -> barrier (NO vm drain: A(kb+1) in flight)
        asm volatile("s_waitcnt lgkmcnt(0)" ::: "memory");
        __builtin_amdgcn_sched_barrier(0);
        __builtin_amdgcn_s_barrier();
        __builtin_amdgcn_sched_barrier(0);

        if (kb < 15) {              // B(kb+1): safe now, covered by MFMAs
            const int kn = kb + 1;
            #pragma unroll
            for (int i = 0; i < 4; ++i) {
                int chunk = wave * 4 + i;
                LOAD_LDS16(Bp0 + (size_t)kn * 8192 + chunk * 512 + lane * 8,
                           &lsB[0][chunk * 512]);
                LOAD_LDS16(Bp1 + (size_t)kn * 8192 + chunk * 512 + lane * 8,
                           &lsB[1][chunk * 512]);
            }
        }

        __builtin_amdgcn_s_setprio(1);
        #pragma unroll
        for (int kh = 0; kh < 2; ++kh)
            #pragma unroll
            for (int T = 0; T < 2; ++T)
                #pragma unroll
                for (int mi = 0; mi < 4; ++mi)
                    #pragma unroll
                    for (int ni = 0; ni < 4; ++ni)
                        acc[T][mi][ni] = __builtin_amdgcn_mfma_f32_16x16x32_bf16(
                            af[kh][mi], bfr[kh][T][ni], acc[T][mi][ni], 0, 0, 0);
        __builtin_amdgcn_s_setprio(0);
    }

    // ---- epilogue: gates, c RMW (global fp32), h write, pred partials ----
    int uu[2];
    uu[0] = (2 * p) * 32 + wc * 16 + l15;
    uu[1] = uu[0] + 32;
    float g_b[2][4], g_w[2][4], w1u[2];
    #pragma unroll
    for (int T = 0; T < 2; ++T) {
        #pragma unroll
        for (int g = 0; g < 4; ++g) {
            g_b[T][g] = bias[g * 1024 + uu[T]];
            g_w[T][g] = Wx[g * 1024 + uu[T]];
        }
        w1u[T] = w1[uu[T]];
    }
    const bool do_pred = (t >= SEQ - 1);

    #pragma unroll
    for (int mi = 0; mi < 4; ++mi) {
        #pragma unroll
        for (int r = 0; r < 4; ++r) {
            int rl   = rbase + mi * 16 + quad * 4 + r;
            int brow = G * 128 + rl;
            float xv = lsX[rl];
            float ps = 0.f;
            #pragma unroll
            for (int T = 0; T < 2; ++T) {
                float zi = acc[T][mi][0][r] + g_b[T][0] + xv * g_w[T][0];
                float zf = acc[T][mi][1][r] + g_b[T][1] + xv * g_w[T][1];
                float zg = acc[T][mi][2][r] + g_b[T][2] + xv * g_w[T][2];
                float zo = acc[T][mi][3][r] + g_b[T][3] + xv * g_w[T][3];
                float ig = fsig(zi), fg = fsig(zf);
                float gg = ftanh(zg), og = fsig(zo);
                size_t off = (size_t)brow * U_SZ + uu[T];
                float cn = fg * cst[off] + ig * gg;
                cst[off] = cn;
                float hv = og * ftanh(cn);
                hout[off] = (bf16_t)hv;
                ps += hv * w1u[T];
            }
            if (do_pred) {
                ps += __shfl_xor(ps, 1);
                ps += __shfl_xor(ps, 2);
                ps += __shfl_xor(ps, 4);
                ps += __shfl_xor(ps, 8);
                if (l15 == 0) atomicAdd(&pr_acc[brow], ps);
            }
        }
    }
}

// final output slot 199 from praw of step 203 (203 % 3 == 2)
__global__ void pred_final(const float* __restrict__ praw,
                           const float* __restrict__ b1,
                           const float* __restrict__ w2,
                           const float* __restrict__ b2,
                           float* __restrict__ out)
{
    int row = blockIdx.x * 256 + threadIdx.x;
    float x1 = fmaxf(praw[2 * B_SZ + row] + b1[0], 0.f);
    out[(size_t)row * TSTEPS + 199] = x1 * w2[0] + b2[0];
}

extern "C" void kernel_launch(void* const* d_in, const int* in_sizes, int n_in,
                              void* d_out, int out_size, void* d_ws, size_t ws_size,
                              hipStream_t stream) {
    const float* inputs = (const float*)d_in[0];   // [4096,5,1]
    const float* Wx     = (const float*)d_in[1];   // [1,4096]
    const float* R      = (const float*)d_in[2];   // [1024,4096]
    const float* bias   = (const float*)d_in[3];   // [4096]
    const float* w1     = (const float*)d_in[4];   // [1024,1]
    const float* b1     = (const float*)d_in[5];
    const float* w2     = (const float*)d_in[6];
    const float* b2     = (const float*)d_in[7];
    float* out = (float*)d_out;

    char* ws = (char*)d_ws;
    const size_t RP_BYTES = (size_t)32 * 131072 * 2;          // 8 MB
    const size_t H_BYTES  = (size_t)B_SZ * U_SZ * 2;          // 8 MB
    const size_t C_BYTES  = (size_t)B_SZ * U_SZ * 4;          // 16 MB
    bf16_t* Rp   = (bf16_t*)ws;                ws += RP_BYTES;
    bf16_t* h0   = (bf16_t*)ws;                ws += H_BYTES;
    bf16_t* h1   = (bf16_t*)ws;                ws += H_BYTES;
    float*  cbuf = (float*)ws;                 ws += C_BYTES;
    float*  praw = (float*)ws;                 ws += 3 * B_SZ * 4;
    bf16_t* hb[2] = {h0, h1};

    hipMemsetAsync(h0, 0, H_BYTES, stream);
    hipMemsetAsync(cbuf, 0, C_BYTES, stream);
    hipMemsetAsync(praw, 0, 3 * B_SZ * 4, stream);

    pack_R<<<16384, 256, 0, stream>>>(R, Rp);

    dim3 grid(16, 32);   // linear bid -> 2-D XCD tile decode in-kernel
    int cur = 0;
    for (int t = 0; t < STEPS; ++t) {
        lstm_step<<<grid, 256, 0, stream>>>(hb[cur], hb[1 - cur], cbuf, Rp,
                                            Wx, bias, w1, b1, w2, b2,
                                            inputs, praw, out, t);
        cur ^= 1;
    }
    pred_final<<<16, 256, 0, stream>>>(praw, b1, w2, b2, out);
}